// Round 1
// baseline (11213.613 us; speedup 1.0000x reference)
//
#include <hip/hip_runtime.h>

// Problem constants
#define Tt    1024
#define INF   256
#define Hh    768
#define OUTF  128

// Grid: 48 L0 + 48 L1 + 2 LIN WGs, 1024 thr each.
// Batch 32 split into 2 halves of 16; iteration i = (half i&1, timestep i>>1).
// Every dependency edge is >=2 iterations apart -> LLC round trip overlapped.
#define NWG_L0  48
#define NWG_L1  48
#define NWG_LIN 2
#define NWG     (NWG_L0 + NWG_L1 + NWG_LIN)   // 98
#define NTHR    1024
#define NIT     (2 * Tt + 4)                  // 2052 iterations

typedef unsigned int       u32;
typedef unsigned long long u64;
typedef unsigned short     u16;
typedef __attribute__((ext_vector_type(8))) short bf16x8;   // 8 bf16 = 4 VGPRs
typedef __attribute__((ext_vector_type(4))) float f32x4;    // MFMA C/D

// ws layout (bytes). prog[wg]: PRIVATE 128-B line, 1 writer, N pollers.
// h rings: [2 half][3 par][16 rows][768 j] bf16 per layer output.
#define PROG_OFF 0
#define HPS16    12288                        // u16 per [16][768] slab
#define HA_OFF   16384
#define HB_OFF   (HA_OFF + 6 * HPS16 * 2)     // 163840
#define WS_BYTES (HB_OFF + 6 * HPS16 * 2)     // 311296

// act LDS row strides (bytes). All multiples of 128 -> XOR swizzle stays in-row.
#define AST0  2048       // L0: 1024 cols bf16 (x 256 | hA 768)
#define AST1  3072       // L1: 1536 cols bf16 (hA 768 | hB 768)
#define AST2  1536       // LIN: 768 cols bf16 (hB)
#define RSLAB 272        // red slab stride (dw)
#define RROW  17         // red row stride (dw)

__device__ __forceinline__ float sigf(float v){ return 1.0f/(1.0f+__expf(-v)); }
__device__ __forceinline__ float tanhfast(float x){
    const float cx = fminf(fmaxf(x, -15.f), 15.f);
    const float e  = __expf(2.f * cx);
    return (e - 1.f) / (e + 1.f);
}
__device__ __forceinline__ u16 f2bf(float f){           // round-nearest-even
    u32 u = __float_as_uint(f);
    return (u16)((u + 0x7fffu + ((u>>16)&1u)) >> 16);
}
// LLC-coherent (L1/L2-bypassing) accesses for cross-WG data.
__device__ __forceinline__ void st32ws(u16* p, u32 v){
    __hip_atomic_store((u32*)p, v, __ATOMIC_RELAXED, __HIP_MEMORY_SCOPE_AGENT);
}
__device__ __forceinline__ u32 ldu32(const u32* p){
    return __hip_atomic_load(p, __ATOMIC_RELAXED, __HIP_MEMORY_SCOPE_AGENT);
}
__device__ __forceinline__ void stu32(u32* p, u32 v){
    __hip_atomic_store(p, v, __ATOMIC_RELAXED, __HIP_MEMORY_SCOPE_AGENT);
}
// 16-B cache-bypassing loads, batched, single vmcnt drain.
__device__ __forceinline__ void ld16x2(const u16* p0, const u16* p1,
                                       f32x4& r0, f32x4& r1){
    asm volatile(
        "global_load_dwordx4 %0, %2, off sc0 sc1\n\t"
        "global_load_dwordx4 %1, %3, off sc0 sc1\n\t"
        "s_waitcnt vmcnt(0)"
        : "=&v"(r0), "=&v"(r1)
        : "v"(p0), "v"(p1)
        : "memory");
}
__device__ __forceinline__ void ld16x4(const u16* p0, const u16* p1,
                                       const u16* p2, const u16* p3,
                                       f32x4& r0, f32x4& r1, f32x4& r2, f32x4& r3){
    asm volatile(
        "global_load_dwordx4 %0, %4, off sc0 sc1\n\t"
        "global_load_dwordx4 %1, %5, off sc0 sc1\n\t"
        "global_load_dwordx4 %2, %6, off sc0 sc1\n\t"
        "global_load_dwordx4 %3, %7, off sc0 sc1\n\t"
        "s_waitcnt vmcnt(0)"
        : "=&v"(r0), "=&v"(r1), "=&v"(r2), "=&v"(r3)
        : "v"(p0), "v"(p1), "v"(p2), "v"(p3)
        : "memory");
}

// Gang-poll cnt lines [base, base+cnt) for prog >= thr. Call from one wave.
__device__ __forceinline__ void waitlines(u32* prog, int base, int cnt, u32 thr, int lane){
    bool ok = (lane >= cnt);
    int guard = 0;
    while (guard < (1 << 24)) {
        if (!ok) ok = (ldu32(prog + (base + lane) * 32) >= thr);
        if (__ballot(ok) == ~0ull) break;
        __builtin_amdgcn_s_sleep(1);
        ++guard;
    }
}

__global__ void prologue(char* ws){
    int i = blockIdx.x * 256 + threadIdx.x;
    if (i < WS_BYTES / 4)
        __hip_atomic_store(((u32*)ws) + i, 0u, __ATOMIC_RELAXED, __HIP_MEMORY_SCOPE_AGENT);
}

__device__ __forceinline__ bf16x8 load8w(const float* p){
    float4 v0 = *(const float4*)(p);
    float4 v1 = *(const float4*)(p + 4);
    bf16x8 r;
    r[0]=(short)f2bf(v0.x); r[1]=(short)f2bf(v0.y); r[2]=(short)f2bf(v0.z); r[3]=(short)f2bf(v0.w);
    r[4]=(short)f2bf(v1.x); r[5]=(short)f2bf(v1.y); r[6]=(short)f2bf(v1.z); r[7]=(short)f2bf(v1.w);
    return r;
}

__global__ __launch_bounds__(NTHR) void lstm_persist(
    const float* __restrict__ x,
    const float* __restrict__ Wih0, const float* __restrict__ Whh0,
    const float* __restrict__ bih0, const float* __restrict__ bhh0,
    const float* __restrict__ Wih1, const float* __restrict__ Whh1,
    const float* __restrict__ bih1, const float* __restrict__ bhh1,
    const float* __restrict__ Wlin, const float* __restrict__ blin,
    float* __restrict__ out, char* ws)
{
    u32* prog = (u32*)(ws + PROG_OFF);
    u16* hA   = (u16*)(ws + HA_OFF);
    u16* hB   = (u16*)(ws + HB_OFF);

    const int wg  = blockIdx.x;
    const int tid = threadIdx.x;

    // act max = 49152 (L1). red (17408 B) disjoint for L0/LIN, aliased at 0 for L1.
    __shared__ __align__(16) char smem[50176];

    const int lane = tid & 63, w = tid >> 6;
    const int quad = lane >> 4, nl = lane & 15;
    const int nt = w >> 2, ks = w & 3;          // gate-tile 0..3, K-slice 0..3
    const int srow = tid & 15, g2 = tid >> 4;   // staging map: row, 32B-chunk group

    const int role  = (wg < NWG_L0) ? 0 : ((wg < NWG_L0 + NWG_L1) ? 1 : 2);
    const int jbase = (role == 0) ? wg * 16 : ((role == 1) ? (wg - NWG_L0) * 16 : 0);
    const int obase = (role == 2) ? (wg - NWG_L0 - NWG_L1) * 64 : 0;

    char*  actb = smem;
    float* red  = (float*)(smem + ((role == 0) ? 32768 : (role == 1) ? 0 : 24576));

    // ---- register-resident bf16 weights (B-frags), loaded ONCE ----
    // B-frag layout: n = lane&15, k = quad*8 + j.
    bf16x8 bfr[12];
    if (role == 0) {
        const int grow = nt * Hh + jbase + nl;
        #pragma unroll
        for (int fi = 0; fi < 8; ++fi) {
            const int ka = ks * 256 + fi * 32 + quad * 8;      // K: [x(256); hA(768)]
            const float* p = (ka < 256) ? (Wih0 + (size_t)grow * 256 + ka)
                                        : (Whh0 + (size_t)grow * 768 + (ka - 256));
            bfr[fi] = load8w(p);
        }
    } else if (role == 1) {
        const int grow = nt * Hh + jbase + nl;
        #pragma unroll
        for (int fi = 0; fi < 12; ++fi) {
            const int ka = ks * 384 + fi * 32 + quad * 8;      // K: [hA(768); hB(768)]
            const float* p = (ka < 768) ? (Wih1 + (size_t)grow * 768 + ka)
                                        : (Whh1 + (size_t)grow * 768 + (ka - 768));
            bfr[fi] = load8w(p);
        }
    } else {
        const int row = obase + nt * 16 + nl;
        #pragma unroll
        for (int fi = 0; fi < 6; ++fi) {
            const int ka = ks * 192 + fi * 32 + quad * 8;
            bfr[fi] = load8w(Wlin + (size_t)row * 768 + ka);
        }
    }

    // gate threads (tid<128): (j-pair jj = tid>>4, row b2 = tid&15); c per half in regs
    float ba0=0,ba1=0,ba2=0,ba3=0, bb0=0,bb1=0,bb2=0,bb3=0;
    float c00=0, c01=0, c10=0, c11=0;           // c[half][j0/j1]
    float bl = 0.f;
    if (role < 2 && tid < 128) {
        const int jg0 = jbase + 2 * (tid >> 4), jg1 = jg0 + 1;
        const float* bi = (role == 0) ? bih0 : bih1;
        const float* bh = (role == 0) ? bhh0 : bhh1;
        ba0 = bi[jg0]        + bh[jg0];        bb0 = bi[jg1]        + bh[jg1];
        ba1 = bi[768 + jg0]  + bh[768 + jg0];  bb1 = bi[768 + jg1]  + bh[768 + jg1];
        ba2 = bi[1536 + jg0] + bh[1536 + jg0]; bb2 = bi[1536 + jg1] + bh[1536 + jg1];
        ba3 = bi[2304 + jg0] + bh[2304 + jg0]; bb3 = bi[2304 + jg1] + bh[2304 + jg1];
    }
    if (role == 2) bl = blin[obase + (tid >> 4)];

    for (int i = 0; i < NIT; ++i) {
        const int t = i >> 1, half = i & 1;
        const int pr0 = t % 3, pr1 = (t + 1) % 3, pr2 = (t + 2) % 3;
        // role0: reads hA(half,t-1)@pr2, writes hA(half,t)@pr0
        // role1: reads hA(half,t-1)@pr2 + hB(half,t-2)@pr1, writes hB(half,t-1)@pr2
        // role2: reads hB(half,t-2)@pr1
        const bool active = (role == 0) ? (i < 2 * Tt)
                          : (role == 1) ? (i >= 2 && i < 2 * Tt + 2)
                          :               (i >= 4);

        // ---- dependency polling: waves 0 and 1 poll in PARALLEL ----
        if (active) {
            if (role == 0) {
                if (w == 0 && i >= 2) waitlines(prog, 0, 48, (u32)(i - 1), lane);   // own: L0 fin i-2
                if (w == 1 && i >= 4) waitlines(prog, 48, 48, (u32)(i - 3), lane);  // WAR: L1 fin i-4
            } else if (role == 1) {
                if (w == 0) waitlines(prog, 48, 48, (u32)(i - 1), lane);            // own: L1 fin i-2
                if (w == 1) {   // merged: L0 fin i-2 (lanes 0..47) + LIN fin i-4 (48..49)
                    const u32 thr2 = (lane < 48) ? (u32)(i - 1)
                                                 : ((i >= 4) ? (u32)(i - 3) : 0u);
                    const int idx  = (lane < 48) ? lane : (96 + (lane - 48));
                    bool ok = (lane >= 50);
                    int guard = 0;
                    while (guard < (1 << 24)) {
                        if (!ok) ok = (ldu32(prog + idx * 32) >= thr2);
                        if (__ballot(ok) == ~0ull) break;
                        __builtin_amdgcn_s_sleep(1);
                        ++guard;
                    }
                }
            } else {
                if (w == 0) waitlines(prog, 48, 48, (u32)(i - 1), lane);            // L1 fin i-2
            }
        }
        __syncthreads();   // B1

        if (active) {
            // ---- single-pass staging into XOR-swizzled act ----
            // write byte = (row*AST + 32B-chunk) ^ ((row&7)<<4); AST % 128 == 0.
            const u32 swz = (u32)((srow & 7) << 4);
            if (role == 0) {
                const u32 c0 = (u32)(srow * AST0 + g2 * 32);
                if (g2 < 16) {
                    const int trow = half * 16 + srow;
                    const float* xs = x + ((size_t)trow * Tt + t) * INF + g2 * 16;
                    const float4 v0 = ((const float4*)xs)[0];
                    const float4 v1 = ((const float4*)xs)[1];
                    const float4 v2 = ((const float4*)xs)[2];
                    const float4 v3 = ((const float4*)xs)[3];
                    uint4 a, b;
                    a.x = (u32)f2bf(v0.x) | ((u32)f2bf(v0.y) << 16);
                    a.y = (u32)f2bf(v0.z) | ((u32)f2bf(v0.w) << 16);
                    a.z = (u32)f2bf(v1.x) | ((u32)f2bf(v1.y) << 16);
                    a.w = (u32)f2bf(v1.z) | ((u32)f2bf(v1.w) << 16);
                    b.x = (u32)f2bf(v2.x) | ((u32)f2bf(v2.y) << 16);
                    b.y = (u32)f2bf(v2.z) | ((u32)f2bf(v2.w) << 16);
                    b.z = (u32)f2bf(v3.x) | ((u32)f2bf(v3.y) << 16);
                    b.w = (u32)f2bf(v3.z) | ((u32)f2bf(v3.w) << 16);
                    *(uint4*)(actb + (c0 ^ swz))        = a;
                    *(uint4*)(actb + ((c0 + 16) ^ swz)) = b;
                } else {
                    const u16* hp = hA + (size_t)(half * 3 + pr2) * HPS16
                                       + srow * 768 + (g2 - 16) * 16;
                    f32x4 r0, r1;
                    ld16x2(hp, hp + 8, r0, r1);
                    *(f32x4*)(actb + (c0 ^ swz))        = r0;
                    *(f32x4*)(actb + ((c0 + 16) ^ swz)) = r1;
                }
            } else if (role == 1) {
                const u16* pA = hA + (size_t)(half * 3 + pr2) * HPS16 + srow * 768;
                const u16* pB = hB + (size_t)(half * 3 + pr1) * HPS16 + srow * 768;
                if (g2 < 32) {      // chunks {g2 (hA), g2+64 (hB)}
                    const u16* p1 = pA + g2 * 16;
                    const u16* p2 = pB + (g2 + 16) * 16;
                    f32x4 r0, r1, r2, r3;
                    ld16x4(p1, p1 + 8, p2, p2 + 8, r0, r1, r2, r3);
                    const u32 c0 = (u32)(srow * AST1 + g2 * 32);
                    const u32 c1 = (u32)(srow * AST1 + (g2 + 64) * 32);
                    *(f32x4*)(actb + (c0 ^ swz))        = r0;
                    *(f32x4*)(actb + ((c0 + 16) ^ swz)) = r1;
                    *(f32x4*)(actb + (c1 ^ swz))        = r2;
                    *(f32x4*)(actb + ((c1 + 16) ^ swz)) = r3;
                } else {            // chunk g2: 32..47 hA, 48..63 hB
                    const u16* p1 = (g2 < 48) ? (pA + g2 * 16) : (pB + (g2 - 48) * 16);
                    f32x4 r0, r1;
                    ld16x2(p1, p1 + 8, r0, r1);
                    const u32 c0 = (u32)(srow * AST1 + g2 * 32);
                    *(f32x4*)(actb + (c0 ^ swz))        = r0;
                    *(f32x4*)(actb + ((c0 + 16) ^ swz)) = r1;
                }
            } else {
                if (tid < 768) {
                    const u16* pB = hB + (size_t)(half * 3 + pr1) * HPS16
                                       + srow * 768 + g2 * 16;
                    f32x4 r0, r1;
                    ld16x2(pB, pB + 8, r0, r1);
                    const u32 c0 = (u32)(srow * AST2 + g2 * 32);
                    *(f32x4*)(actb + (c0 ^ swz))        = r0;
                    *(f32x4*)(actb + ((c0 + 16) ^ swz)) = r1;
                }
            }
            __syncthreads();   // B2: act ready

            // ---- MFMA: one C tile per wave (16 rows x 16 gate-cols, K-slice ks) ----
            f32x4 acc = {0.f, 0.f, 0.f, 0.f};
            const u32 swzr = (u32)((nl & 7) << 4);
            if (role == 0) {
                #pragma unroll
                for (int fc = 0; fc < 8; ++fc) {
                    const u32 off = (u32)(nl * AST0 + (ks * 256 + fc * 32 + quad * 8) * 2);
                    bf16x8 a = *(const bf16x8*)(actb + (off ^ swzr));
                    acc = __builtin_amdgcn_mfma_f32_16x16x32_bf16(a, bfr[fc], acc, 0, 0, 0);
                }
            } else if (role == 1) {
                #pragma unroll
                for (int fc = 0; fc < 12; ++fc) {
                    const u32 off = (u32)(nl * AST1 + (ks * 384 + fc * 32 + quad * 8) * 2);
                    bf16x8 a = *(const bf16x8*)(actb + (off ^ swzr));
                    acc = __builtin_amdgcn_mfma_f32_16x16x32_bf16(a, bfr[fc], acc, 0, 0, 0);
                }
            } else {
                #pragma unroll
                for (int fc = 0; fc < 6; ++fc) {
                    const u32 off = (u32)(nl * AST2 + (ks * 192 + fc * 32 + quad * 8) * 2);
                    bf16x8 a = *(const bf16x8*)(actb + (off ^ swzr));
                    acc = __builtin_amdgcn_mfma_f32_16x16x32_bf16(a, bfr[fc], acc, 0, 0, 0);
                }
            }
            if (role == 1) __syncthreads();   // L1 only: red aliases act
            // D layout: col n = lane&15, row m = quad*4 + reg.
            *(f32x4*)(red + (size_t)(nt * 4 + ks) * RSLAB + nl * RROW + quad * 4) = acc;
            __syncthreads();   // B3: red ready

            if (role == 2) {
                const int lt = t - 2;
                const int oc = tid >> 4, orow = tid & 15;
                float ssum = bl;
                #pragma unroll
                for (int k2 = 0; k2 < 4; ++k2)
                    ssum += red[(size_t)((oc >> 4) * 4 + k2) * RSLAB + (oc & 15) * RROW + orow];
                out[((size_t)(half * 16 + orow) * Tt + lt) * OUTF + obase + oc] = ssum;
            } else if (tid < 128) {
                // ---- fused K-reduce + gates + packed h store ----
                const int jj = tid >> 4, b2 = tid & 15;
                const int j0 = 2 * jj, j1 = j0 + 1;
                float p0a=0,p1a=0,p2a=0,p3a=0, p0b=0,p1b=0,p2b=0,p3b=0;
                #pragma unroll
                for (int k2 = 0; k2 < 4; ++k2) {
                    p0a += red[(size_t)(0 * 4 + k2) * RSLAB + j0 * RROW + b2];
                    p1a += red[(size_t)(1 * 4 + k2) * RSLAB + j0 * RROW + b2];
                    p2a += red[(size_t)(2 * 4 + k2) * RSLAB + j0 * RROW + b2];
                    p3a += red[(size_t)(3 * 4 + k2) * RSLAB + j0 * RROW + b2];
                    p0b += red[(size_t)(0 * 4 + k2) * RSLAB + j1 * RROW + b2];
                    p1b += red[(size_t)(1 * 4 + k2) * RSLAB + j1 * RROW + b2];
                    p2b += red[(size_t)(2 * 4 + k2) * RSLAB + j1 * RROW + b2];
                    p3b += red[(size_t)(3 * 4 + k2) * RSLAB + j1 * RROW + b2];
                }
                float cA = half ? c10 : c00;
                float cB = half ? c11 : c01;
                const float ig0 = sigf(ba0 + p0a), fg0 = sigf(ba1 + p1a);
                const float gv0 = tanhfast(ba2 + p2a), og0 = sigf(ba3 + p3a);
                cA = fg0 * cA + ig0 * gv0;
                const float h0 = og0 * tanhfast(cA);
                const float ig1 = sigf(bb0 + p0b), fg1 = sigf(bb1 + p1b);
                const float gv1 = tanhfast(bb2 + p2b), og1 = sigf(bb3 + p3b);
                cB = fg1 * cB + ig1 * gv1;
                const float h1 = og1 * tanhfast(cB);
                if (half) { c10 = cA; c11 = cB; } else { c00 = cA; c01 = cB; }
                const int parW = (role == 0) ? pr0 : pr2;
                u16* dst = ((role == 0) ? hA : hB) + (size_t)(half * 3 + parW) * HPS16;
                st32ws(dst + b2 * 768 + jbase + j0,
                       (u32)f2bf(h0) | ((u32)f2bf(h1) << 16));
            }
        }

        // ---- publish progress (barrier drains all stores first) ----
        __syncthreads();   // B4
        if (tid == 0) stu32(prog + wg * 32, (u32)(i + 1));
    }
}

extern "C" void kernel_launch(void* const* d_in, const int* in_sizes, int n_in,
                              void* d_out, int out_size, void* d_ws, size_t ws_size,
                              hipStream_t stream)
{
    const float* x    = (const float*)d_in[0];
    const float* Wih0 = (const float*)d_in[1];
    const float* Whh0 = (const float*)d_in[2];
    const float* bih0 = (const float*)d_in[3];
    const float* bhh0 = (const float*)d_in[4];
    const float* Wih1 = (const float*)d_in[5];
    const float* Whh1 = (const float*)d_in[6];
    const float* bih1 = (const float*)d_in[7];
    const float* bhh1 = (const float*)d_in[8];
    const float* Wlin = (const float*)d_in[9];
    const float* blin = (const float*)d_in[10];
    float* out = (float*)d_out;
    char*  ws  = (char*)d_ws;   // uses WS_BYTES = 311296 B

    hipLaunchKernelGGL(prologue, dim3(304), dim3(256), 0, stream, ws);
    hipLaunchKernelGGL(lstm_persist, dim3(NWG), dim3(NTHR), 0, stream,
                       x, Wih0, Whh0, bih0, bhh0,
                       Wih1, Whh1, bih1, bhh1,
                       Wlin, blin, out, ws);
}

// Round 2
// 9841.451 us; speedup vs baseline: 1.1394x; 1.1394x over previous
//
#include <hip/hip_runtime.h>

// Problem constants
#define Tt    1024
#define INF   256
#define Hh    768
#define OUTF  128

// Grid: 96 L0 + 96 L1 + 2 LIN WGs, 1024 thr each. Full batch (32) per iteration.
// L0/L1 WG owns 8 h-columns x 4 gates. Waves load MFMA A-fragments DIRECTLY from
// LLC (ws) into VGPRs -- no LDS activation staging, 2 barriers/iter.
// Sync: per-role aggregated epoch counters (atomicAdd, slot s&3, monotone
// threshold N*(s/4+1)); wave 0 polls globally, other waves spin on LDS rdy.
#define NWG_L0  96
#define NWG_L1  96
#define NWG_LIN 2
#define NWG     (NWG_L0 + NWG_L1 + NWG_LIN)   // 194
#define NTHR    1024
#define NIT     (Tt + 2)                      // 1026 iterations

typedef unsigned int       u32;
typedef unsigned short     u16;
typedef __attribute__((ext_vector_type(8))) short bf16x8;   // 8 bf16 = 4 VGPRs
typedef __attribute__((ext_vector_type(4))) float f32x4;    // MFMA C/D

// ws layout (bytes).
// ctr: [3 role][4 par] epoch counters, each on its own 128-B line.
// h rings: [3 par][32 rows][768 j] bf16 per layer.
#define CTR_OFF  0
#define HPS      24576                        // u16 per [32][768] slab
#define HA_OFF   16384
#define HB_OFF   (HA_OFF + 3 * 49152)         // 163840
#define WS_BYTES (HB_OFF + 3 * 49152)         // 311296

#define RSLAB 272        // red slab stride (dw)
#define RROW  17         // red col stride (dw)

__device__ __forceinline__ float sigf(float v){ return 1.0f/(1.0f+__expf(-v)); }
__device__ __forceinline__ float tanhfast(float x){
    const float cx = fminf(fmaxf(x, -15.f), 15.f);
    const float e  = __expf(2.f * cx);
    return (e - 1.f) / (e + 1.f);
}
__device__ __forceinline__ u16 f2bf(float f){           // round-nearest-even
    u32 u = __float_as_uint(f);
    return (u16)((u + 0x7fffu + ((u>>16)&1u)) >> 16);
}
// LLC-coherent (L1/L2-bypassing) accesses for cross-WG data.
__device__ __forceinline__ void st32ws(u16* p, u32 v){
    __hip_atomic_store((u32*)p, v, __ATOMIC_RELAXED, __HIP_MEMORY_SCOPE_AGENT);
}
__device__ __forceinline__ u32 ldu32(const u32* p){
    return __hip_atomic_load(p, __ATOMIC_RELAXED, __HIP_MEMORY_SCOPE_AGENT);
}

// Batched cache-bypassing A-fragment loads: N x 16B at 64-B stride from one
// base, single vmcnt drain in the SAME asm block (no hoisting hazard: the
// consuming MFMAs depend on the outputs of this block).
__device__ __forceinline__ void issue4w(const u16* p, f32x4& r0, f32x4& r1,
                                        f32x4& r2, f32x4& r3){
    asm volatile(
        "global_load_dwordx4 %0, %4, off sc0 sc1\n\t"
        "global_load_dwordx4 %1, %4, off offset:64 sc0 sc1\n\t"
        "global_load_dwordx4 %2, %4, off offset:128 sc0 sc1\n\t"
        "global_load_dwordx4 %3, %4, off offset:192 sc0 sc1\n\t"
        "s_waitcnt vmcnt(0)"
        : "=&v"(r0), "=&v"(r1), "=&v"(r2), "=&v"(r3)
        : "v"(p) : "memory");
}
__device__ __forceinline__ void issue6w(const u16* p, f32x4& r0, f32x4& r1,
                                        f32x4& r2, f32x4& r3, f32x4& r4, f32x4& r5){
    asm volatile(
        "global_load_dwordx4 %0, %6, off sc0 sc1\n\t"
        "global_load_dwordx4 %1, %6, off offset:64 sc0 sc1\n\t"
        "global_load_dwordx4 %2, %6, off offset:128 sc0 sc1\n\t"
        "global_load_dwordx4 %3, %6, off offset:192 sc0 sc1\n\t"
        "global_load_dwordx4 %4, %6, off offset:256 sc0 sc1\n\t"
        "global_load_dwordx4 %5, %6, off offset:320 sc0 sc1\n\t"
        "s_waitcnt vmcnt(0)"
        : "=&v"(r0), "=&v"(r1), "=&v"(r2), "=&v"(r3), "=&v"(r4), "=&v"(r5)
        : "v"(p) : "memory");
}

#define BC(v) __builtin_bit_cast(bf16x8, v)

// Uniform counter polls (all lanes load the same line).
__device__ __forceinline__ void wait1p(const u32* a, u32 ta){
    int g = 0;
    while (g < (1 << 24) && ldu32(a) < ta) { __builtin_amdgcn_s_sleep(1); ++g; }
}
__device__ __forceinline__ void wait2p(const u32* a, u32 ta, const u32* b, u32 tb){
    int g = 0;
    while (g < (1 << 24)) {
        if (ldu32(a) >= ta && ldu32(b) >= tb) break;
        __builtin_amdgcn_s_sleep(1); ++g;
    }
}
__device__ __forceinline__ void wait3p(const u32* a, u32 ta, const u32* b, u32 tb,
                                       const u32* c, u32 tc){
    int g = 0;
    while (g < (1 << 24)) {
        if (ldu32(a) >= ta && ldu32(b) >= tb && ldu32(c) >= tc) break;
        __builtin_amdgcn_s_sleep(1); ++g;
    }
}

__global__ void prologue(char* ws){
    int i = blockIdx.x * 256 + threadIdx.x;
    if (i < WS_BYTES / 4)
        __hip_atomic_store(((u32*)ws) + i, 0u, __ATOMIC_RELAXED, __HIP_MEMORY_SCOPE_AGENT);
}

__device__ __forceinline__ bf16x8 load8w(const float* p){
    float4 v0 = *(const float4*)(p);
    float4 v1 = *(const float4*)(p + 4);
    bf16x8 r;
    r[0]=(short)f2bf(v0.x); r[1]=(short)f2bf(v0.y); r[2]=(short)f2bf(v0.z); r[3]=(short)f2bf(v0.w);
    r[4]=(short)f2bf(v1.x); r[5]=(short)f2bf(v1.y); r[6]=(short)f2bf(v1.z); r[7]=(short)f2bf(v1.w);
    return r;
}

__global__ __launch_bounds__(NTHR) void lstm_persist(
    const float* __restrict__ x,
    const float* __restrict__ Wih0, const float* __restrict__ Whh0,
    const float* __restrict__ bih0, const float* __restrict__ bhh0,
    const float* __restrict__ Wih1, const float* __restrict__ Whh1,
    const float* __restrict__ bih1, const float* __restrict__ bhh1,
    const float* __restrict__ Wlin, const float* __restrict__ blin,
    float* __restrict__ out, char* ws)
{
    u32* ctr = (u32*)(ws + CTR_OFF);          // line (role*4+par)*32 u32
    u16* hA  = (u16*)(ws + HA_OFF);
    u16* hB  = (u16*)(ws + HB_OFF);

    const int wg  = blockIdx.x;
    const int tid = threadIdx.x;

    __shared__ __align__(16) float red[32 * RSLAB];   // 34816 B
    __shared__ u32 rdy;

    const int lane = tid & 63, w = tid >> 6;
    const int quad = lane >> 4, nl = lane & 15;
    const int mwv = w >> 3, ks = w & 7;       // roles 0/1: m-half, K-slice
    const int ntL = w >> 2, ksL = w & 3;      // role 2: n-tile, K-slice

    const int role  = (wg < NWG_L0) ? 0 : ((wg < NWG_L0 + NWG_L1) ? 1 : 2);
    const int jbase = (role == 0) ? wg * 8 : ((role == 1) ? (wg - NWG_L0) * 8 : 0);
    const int obase = (role == 2) ? (wg - NWG_L0 - NWG_L1) * 64 : 0;

    // ---- register-resident bf16 weights (B-frags), loaded ONCE ----
    // B-frag: n = lane&15, k = quad*8 + j. WG n-cols: 4 gates x 8 j ->
    // n-tile nt covers gates {2nt, 2nt+1}: grow = (nt*2 + (nl>>3))*768 + jbase + (nl&7).
    bf16x8 bfr[12];
    if (role == 0) {
        #pragma unroll
        for (int nt = 0; nt < 2; ++nt) {
            const int grow = (nt * 2 + (nl >> 3)) * Hh + jbase + (nl & 7);
            #pragma unroll
            for (int fi = 0; fi < 4; ++fi) {
                const int ka = ks * 128 + fi * 32 + quad * 8;   // K: [x(256); hA(768)]
                const float* p = (ka < 256) ? (Wih0 + (size_t)grow * 256 + ka)
                                            : (Whh0 + (size_t)grow * 768 + (ka - 256));
                bfr[nt * 4 + fi] = load8w(p);
            }
        }
    } else if (role == 1) {
        #pragma unroll
        for (int nt = 0; nt < 2; ++nt) {
            const int grow = (nt * 2 + (nl >> 3)) * Hh + jbase + (nl & 7);
            #pragma unroll
            for (int fi = 0; fi < 6; ++fi) {
                const int ka = ks * 192 + fi * 32 + quad * 8;   // K: [hA; hB]
                const float* p = (ka < 768) ? (Wih1 + (size_t)grow * 768 + ka)
                                            : (Whh1 + (size_t)grow * 768 + (ka - 768));
                bfr[nt * 6 + fi] = load8w(p);
            }
        }
    } else {
        const int row = obase + ntL * 16 + nl;
        #pragma unroll
        for (int fi = 0; fi < 6; ++fi) {
            const int ka = ksL * 192 + fi * 32 + quad * 8;
            bfr[fi] = load8w(Wlin + (size_t)row * 768 + ka);
        }
    }

    // gate threads (tid<128): (jj = tid>>5 -> j-pair {2jj,2jj+1}, b2 = tid&31 row)
    float ba0=0,ba1=0,ba2=0,ba3=0, bb0=0,bb1=0,bb2=0,bb3=0, creg0=0, creg1=0;
    float bl0 = 0.f, bl1 = 0.f;
    if (role < 2 && tid < 128) {
        const int jg0 = jbase + 2 * (tid >> 5), jg1 = jg0 + 1;
        const float* bi = (role == 0) ? bih0 : bih1;
        const float* bh = (role == 0) ? bhh0 : bhh1;
        ba0 = bi[jg0]        + bh[jg0];        bb0 = bi[jg1]        + bh[jg1];
        ba1 = bi[768 + jg0]  + bh[768 + jg0];  bb1 = bi[768 + jg1]  + bh[768 + jg1];
        ba2 = bi[1536 + jg0] + bh[1536 + jg0]; bb2 = bi[1536 + jg1] + bh[1536 + jg1];
        ba3 = bi[2304 + jg0] + bh[2304 + jg0]; bb3 = bi[2304 + jg1] + bh[2304 + jg1];
    }
    if (role == 2) {
        bl0 = blin[obase + (tid >> 5)];
        bl1 = blin[obase + 32 + (tid >> 5)];
    }

    if (tid == 0) __hip_atomic_store(&rdy, 0u, __ATOMIC_RELAXED, __HIP_MEMORY_SCOPE_WORKGROUP);
    __syncthreads();

    for (int s = 0; s < NIT; ++s) {
        const int par_wA = s % 3;              // hA(s)    slot
        const int par_rA = (s + 2) % 3;        // hA(s-1)  slot
        const int par_wB = (s + 2) % 3;        // hB(s-1)  slot
        const int par_rB = (s + 1) % 3;        // hB(s-2)  slot
        const bool active = (role == 0) ? (s < Tt)
                          : (role == 1) ? (s >= 1 && s <= Tt)
                          :               (s >= 2);

        // ---- dependency wait: wave 0 polls epoch counters, rest spin on LDS ----
        if (active && w == 0) {
            if (role == 0) {
                if (s >= 2)
                    wait2p(ctr + (0*4 + ((s-1)&3))*32, 96u*((u32)(s-1)/4u + 1u),   // hA(s-1)
                           ctr + (1*4 + ((s-2)&3))*32, 96u*((u32)(s-2)/4u + 1u));  // WAR: L1 fin s-2
                else if (s == 1)
                    wait1p(ctr + (0*4 + 0)*32, 96u);
            } else if (role == 1) {
                if (s >= 2)
                    wait3p(ctr + (0*4 + ((s-1)&3))*32, 96u*((u32)(s-1)/4u + 1u),   // hA(s-1)
                           ctr + (1*4 + ((s-1)&3))*32, 96u*((u32)(s-1)/4u + 1u),   // hB(s-2)
                           ctr + (2*4 + ((s-2)&3))*32,  2u*((u32)(s-2)/4u + 1u));  // WAR: LIN fin s-2
                else
                    wait2p(ctr + (0*4 + 0)*32, 96u, ctr + (1*4 + 0)*32, 96u);
            } else {
                wait1p(ctr + (1*4 + ((s-1)&3))*32, 96u*((u32)(s-1)/4u + 1u));      // hB(s-2)
            }
            if (lane == 0)
                __hip_atomic_store(&rdy, (u32)(s + 1), __ATOMIC_RELAXED, __HIP_MEMORY_SCOPE_WORKGROUP);
        }
        if (active && w != 0 && (role != 0 || ks >= 2)) {
            int g = 0;
            while (g < (1 << 24) &&
                   __hip_atomic_load(&rdy, __ATOMIC_RELAXED, __HIP_MEMORY_SCOPE_WORKGROUP) < (u32)(s + 1)) {
                __builtin_amdgcn_s_sleep(1); ++g;
            }
        }

        if (active) {
            f32x4 acc0 = {0.f,0.f,0.f,0.f}, acc1 = {0.f,0.f,0.f,0.f};

            if (role == 0) {
                if (ks < 2) {
                    // K in [0,256): x(t) direct, in-register convert
                    const float* xr = x + ((size_t)(mwv*16 + nl) * Tt + s) * INF
                                        + ks * 128 + quad * 8;
                    #pragma unroll
                    for (int fi = 0; fi < 4; ++fi) {
                        const bf16x8 af = load8w(xr + fi * 32);
                        acc0 = __builtin_amdgcn_mfma_f32_16x16x32_bf16(af, bfr[fi],     acc0, 0,0,0);
                        acc1 = __builtin_amdgcn_mfma_f32_16x16x32_bf16(af, bfr[4 + fi], acc1, 0,0,0);
                    }
                } else {
                    // K in [256,1024): hA(s-1) direct from LLC
                    const u16* pm = hA + (size_t)par_rA * HPS + (size_t)(mwv*16 + nl) * 768
                                       + (ks - 2) * 128 + quad * 8;
                    f32x4 q0, q1, q2, q3;
                    issue4w(pm, q0, q1, q2, q3);
                    acc0 = __builtin_amdgcn_mfma_f32_16x16x32_bf16(BC(q0), bfr[0], acc0, 0,0,0);
                    acc1 = __builtin_amdgcn_mfma_f32_16x16x32_bf16(BC(q0), bfr[4], acc1, 0,0,0);
                    acc0 = __builtin_amdgcn_mfma_f32_16x16x32_bf16(BC(q1), bfr[1], acc0, 0,0,0);
                    acc1 = __builtin_amdgcn_mfma_f32_16x16x32_bf16(BC(q1), bfr[5], acc1, 0,0,0);
                    acc0 = __builtin_amdgcn_mfma_f32_16x16x32_bf16(BC(q2), bfr[2], acc0, 0,0,0);
                    acc1 = __builtin_amdgcn_mfma_f32_16x16x32_bf16(BC(q2), bfr[6], acc1, 0,0,0);
                    acc0 = __builtin_amdgcn_mfma_f32_16x16x32_bf16(BC(q3), bfr[3], acc0, 0,0,0);
                    acc1 = __builtin_amdgcn_mfma_f32_16x16x32_bf16(BC(q3), bfr[7], acc1, 0,0,0);
                }
            } else if (role == 1) {
                // K in [0,1536) = [hA(s-1) | hB(s-2)], 192 per ks
                const u16* base = (ks < 4) ? (hA + (size_t)par_rA * HPS)
                                           : (hB + (size_t)par_rB * HPS);
                const u16* pm = base + (size_t)(mwv*16 + nl) * 768 + (ks & 3) * 192 + quad * 8;
                f32x4 q0, q1, q2, q3, q4, q5;
                issue6w(pm, q0, q1, q2, q3, q4, q5);
                acc0 = __builtin_amdgcn_mfma_f32_16x16x32_bf16(BC(q0), bfr[0],  acc0, 0,0,0);
                acc1 = __builtin_amdgcn_mfma_f32_16x16x32_bf16(BC(q0), bfr[6],  acc1, 0,0,0);
                acc0 = __builtin_amdgcn_mfma_f32_16x16x32_bf16(BC(q1), bfr[1],  acc0, 0,0,0);
                acc1 = __builtin_amdgcn_mfma_f32_16x16x32_bf16(BC(q1), bfr[7],  acc1, 0,0,0);
                acc0 = __builtin_amdgcn_mfma_f32_16x16x32_bf16(BC(q2), bfr[2],  acc0, 0,0,0);
                acc1 = __builtin_amdgcn_mfma_f32_16x16x32_bf16(BC(q2), bfr[8],  acc1, 0,0,0);
                acc0 = __builtin_amdgcn_mfma_f32_16x16x32_bf16(BC(q3), bfr[3],  acc0, 0,0,0);
                acc1 = __builtin_amdgcn_mfma_f32_16x16x32_bf16(BC(q3), bfr[9],  acc1, 0,0,0);
                acc0 = __builtin_amdgcn_mfma_f32_16x16x32_bf16(BC(q4), bfr[4],  acc0, 0,0,0);
                acc1 = __builtin_amdgcn_mfma_f32_16x16x32_bf16(BC(q4), bfr[10], acc1, 0,0,0);
                acc0 = __builtin_amdgcn_mfma_f32_16x16x32_bf16(BC(q5), bfr[5],  acc0, 0,0,0);
                acc1 = __builtin_amdgcn_mfma_f32_16x16x32_bf16(BC(q5), bfr[11], acc1, 0,0,0);
            } else {
                const u16* pb = hB + (size_t)par_rB * HPS + (size_t)nl * 768 + ksL * 192 + quad * 8;
                f32x4 q0, q1, q2, q3, q4, q5;
                issue6w(pb, q0, q1, q2, q3, q4, q5);
                acc0 = __builtin_amdgcn_mfma_f32_16x16x32_bf16(BC(q0), bfr[0], acc0, 0,0,0);
                acc0 = __builtin_amdgcn_mfma_f32_16x16x32_bf16(BC(q1), bfr[1], acc0, 0,0,0);
                acc0 = __builtin_amdgcn_mfma_f32_16x16x32_bf16(BC(q2), bfr[2], acc0, 0,0,0);
                acc0 = __builtin_amdgcn_mfma_f32_16x16x32_bf16(BC(q3), bfr[3], acc0, 0,0,0);
                acc0 = __builtin_amdgcn_mfma_f32_16x16x32_bf16(BC(q4), bfr[4], acc0, 0,0,0);
                acc0 = __builtin_amdgcn_mfma_f32_16x16x32_bf16(BC(q5), bfr[5], acc0, 0,0,0);
                issue6w(pb + 16 * 768, q0, q1, q2, q3, q4, q5);
                acc1 = __builtin_amdgcn_mfma_f32_16x16x32_bf16(BC(q0), bfr[0], acc1, 0,0,0);
                acc1 = __builtin_amdgcn_mfma_f32_16x16x32_bf16(BC(q1), bfr[1], acc1, 0,0,0);
                acc1 = __builtin_amdgcn_mfma_f32_16x16x32_bf16(BC(q2), bfr[2], acc1, 0,0,0);
                acc1 = __builtin_amdgcn_mfma_f32_16x16x32_bf16(BC(q3), bfr[3], acc1, 0,0,0);
                acc1 = __builtin_amdgcn_mfma_f32_16x16x32_bf16(BC(q4), bfr[4], acc1, 0,0,0);
                acc1 = __builtin_amdgcn_mfma_f32_16x16x32_bf16(BC(q5), bfr[5], acc1, 0,0,0);
            }

            // ---- C tiles -> red. D layout: col n = lane&15, row m = quad*4+reg ----
            if (role < 2) {
                *(f32x4*)&red[(size_t)((mwv    ) * 8 + ks) * RSLAB + nl * RROW + quad * 4] = acc0; // nt0
                *(f32x4*)&red[(size_t)((2 + mwv) * 8 + ks) * RSLAB + nl * RROW + quad * 4] = acc1; // nt1
            } else {
                *(f32x4*)&red[(size_t)((ntL * 2 + 0) * 4 + ksL) * RSLAB + nl * RROW + quad * 4] = acc0;
                *(f32x4*)&red[(size_t)((ntL * 2 + 1) * 4 + ksL) * RSLAB + nl * RROW + quad * 4] = acc1;
            }
            __syncthreads();   // B3: red ready

            if (role == 2) {
                const int v = s - 2;
                const int r2 = tid >> 5, bb = tid & 31;
                const int mtr = bb >> 4, mr2 = bb & 15;
                const int nt0 = r2 >> 4, nr0 = r2 & 15;
                const int nt1 = (r2 + 32) >> 4, nr1 = (r2 + 32) & 15;
                float s0 = 0.f, s1 = 0.f;
                #pragma unroll
                for (int k2 = 0; k2 < 4; ++k2) {
                    s0 += red[(size_t)((nt0 * 2 + mtr) * 4 + k2) * RSLAB + nr0 * RROW + mr2];
                    s1 += red[(size_t)((nt1 * 2 + mtr) * 4 + k2) * RSLAB + nr1 * RROW + mr2];
                }
                float* o = out + ((size_t)bb * Tt + v) * OUTF + obase;
                o[r2]      = s0 + bl0;
                o[32 + r2] = s1 + bl1;
            } else if (tid < 128) {
                // ---- fused K-reduce + gates + packed h store ----
                const int jj = tid >> 5, b2 = tid & 31;
                const int mt = b2 >> 4, mr = b2 & 15;
                float pa[4], pb_[4];
                #pragma unroll
                for (int g = 0; g < 4; ++g) {
                    const int sb = ((g >> 1) * 2 + mt) * 8;
                    const int c0 = (g & 1) * 8 + 2 * jj;
                    float s0 = 0.f, s1 = 0.f;
                    #pragma unroll
                    for (int k2 = 0; k2 < 8; ++k2) {
                        s0 += red[(size_t)(sb + k2) * RSLAB + c0 * RROW + mr];
                        s1 += red[(size_t)(sb + k2) * RSLAB + (c0 + 1) * RROW + mr];
                    }
                    pa[g] = s0; pb_[g] = s1;
                }
                const float ig0 = sigf(ba0 + pa[0]), fg0 = sigf(ba1 + pa[1]);
                const float gv0 = tanhfast(ba2 + pa[2]), og0 = sigf(ba3 + pa[3]);
                creg0 = fg0 * creg0 + ig0 * gv0;
                const float h0 = og0 * tanhfast(creg0);
                const float ig1 = sigf(bb0 + pb_[0]), fg1 = sigf(bb1 + pb_[1]);
                const float gv1 = tanhfast(bb2 + pb_[2]), og1 = sigf(bb3 + pb_[3]);
                creg1 = fg1 * creg1 + ig1 * gv1;
                const float h1 = og1 * tanhfast(creg1);
                u16* dst = (role == 0) ? (hA + (size_t)par_wA * HPS)
                                       : (hB + (size_t)par_wB * HPS);
                st32ws(dst + b2 * 768 + jbase + 2 * jj,
                       (u32)f2bf(h0) | ((u32)f2bf(h1) << 16));
            }
        }

        // ---- publish epoch (barrier drains all stores first) ----
        __syncthreads();   // B_end
        if (tid == 0)
            __hip_atomic_fetch_add(ctr + ((size_t)(role * 4 + (s & 3))) * 32, 1u,
                                   __ATOMIC_RELAXED, __HIP_MEMORY_SCOPE_AGENT);
    }
}

extern "C" void kernel_launch(void* const* d_in, const int* in_sizes, int n_in,
                              void* d_out, int out_size, void* d_ws, size_t ws_size,
                              hipStream_t stream)
{
    const float* x    = (const float*)d_in[0];
    const float* Wih0 = (const float*)d_in[1];
    const float* Whh0 = (const float*)d_in[2];
    const float* bih0 = (const float*)d_in[3];
    const float* bhh0 = (const float*)d_in[4];
    const float* Wih1 = (const float*)d_in[5];
    const float* Whh1 = (const float*)d_in[6];
    const float* bih1 = (const float*)d_in[7];
    const float* bhh1 = (const float*)d_in[8];
    const float* Wlin = (const float*)d_in[9];
    const float* blin = (const float*)d_in[10];
    float* out = (float*)d_out;
    char*  ws  = (char*)d_ws;   // uses WS_BYTES = 311296 B

    hipLaunchKernelGGL(prologue, dim3(304), dim3(256), 0, stream, ws);
    hipLaunchKernelGGL(lstm_persist, dim3(NWG), dim3(NTHR), 0, stream,
                       x, Wih0, Whh0, bih0, bhh0,
                       Wih1, Whh1, bih1, bhh1,
                       Wlin, blin, out, ws);
}